// Round 8
// baseline (974.935 us; speedup 1.0000x reference)
//
#include <hip/hip_runtime.h>

// GCNEncoder: 2x GCNConv(64->64) + BatchNorm + ELU + global_mean_pool
// N=50000, E=800000, D=64, G=64. Inputs f32/int32, output f32.
// R19 284.2 -> R23 276.2 (fused epilogues, atomic storm killed) ->
// R24 276.9 NEUTRAL: deeper in-row ILP + wgt precompute bought nothing ->
//   row-centric gather is structurally latency-bound (deg~16, accumulator
//   serializes; deg variance kills wide steps).
// R25: EDGE-CENTRIC gathers. One block per 128-node dst bucket, acc[128][64]
//   in LDS (32KB); stream partitioned edges with ds_add_f32 (fire-and-forget,
//   no dep chain; every H-row load independent -> BW-bound). Deletes
//   rowptr/col/wfill/csr-scatter; keeps counting-sort partition + fused
//   BN/pool epilogues (per-wave register reduce, replicated scratch).

constexpr int GGRAPHS = 64;
constexpr int EPB = 8192;   // edges per partition block
constexpr int NBK = 128;    // nodes per dst bucket (7 bits)

// cnt[g] via per-block LDS histogram (batch sorted -> storms stay in LDS)
__global__ void cnt_kernel(const int* __restrict__ batch, int* __restrict__ cnt, int n) {
  __shared__ int h[GGRAPHS];
  int t = threadIdx.x;
  if (t < GGRAPHS) h[t] = 0;
  __syncthreads();
  for (int i = blockIdx.x * 256 + t; i < n; i += gridDim.x * 256) {
    int g = batch[i];
    if ((unsigned)g < (unsigned)GGRAPHS) atomicAdd(&h[g], 1);
  }
  __syncthreads();
  if (t < GGRAPHS && h[t] > 0) atomicAdd(&cnt[t], h[t]);
}

// P1: per-block bucket histogram. hist[b*nblk + blk] = #edges of block blk
// with dst in bucket b (bucket = dst>>7, nbuck <= 512).
__global__ void phist_kernel(const int* __restrict__ dst, int* __restrict__ hist,
                             int E, int n, int nblk, int nbuck) {
  __shared__ int h[512];
  int t = threadIdx.x;
  h[t] = 0;
  h[t + 256] = 0;
  __syncthreads();
  int e0 = blockIdx.x * EPB;
  int e1 = e0 + EPB < E ? e0 + EPB : E;
  for (int i = e0 + t; i < e1; i += 256) {
    int d = dst[i];
    if ((unsigned)d < (unsigned)n) atomicAdd(&h[d >> 7], 1);
  }
  __syncthreads();
  for (int bb = t; bb < nbuck; bb += 256) hist[bb * nblk + blockIdx.x] = h[bb];
}

// scan pass 1: per-256-tile exclusive scan; out[i]=local excl, bsum[b]=tile total.
__global__ void scan1_kernel(const int* __restrict__ in, int* __restrict__ out,
                             int* __restrict__ bsum, int n) {
  __shared__ int tmp[256];
  int t = threadIdx.x;
  int i = blockIdx.x * 256 + t;
  int v = (i < n) ? in[i] : 0;
  tmp[t] = v;
  __syncthreads();
#pragma unroll
  for (int off = 1; off < 256; off <<= 1) {
    int a = (t >= off) ? tmp[t - off] : 0;
    __syncthreads();
    tmp[t] += a;
    __syncthreads();
  }
  if (i < n) out[i] = tmp[t] - v;  // exclusive
  if (t == 255) bsum[blockIdx.x] = tmp[255];
}

// scan pass 2: 1 block, exclusive scan of bsum[nb] (nb <= 256); bsum[nb] = total.
__global__ void scan2_kernel(int* __restrict__ bsum, int nb) {
  __shared__ int tmp[256];
  int t = threadIdx.x;
  int v = (t < nb) ? bsum[t] : 0;
  tmp[t] = v;
  __syncthreads();
#pragma unroll
  for (int off = 1; off < 256; off <<= 1) {
    int a = (t >= off) ? tmp[t - off] : 0;
    __syncthreads();
    tmp[t] += a;
    __syncthreads();
  }
  if (t < nb) bsum[t] = tmp[t] - v;
  if (t == 255) bsum[nb] = tmp[255];
}

// scan pass 3: data[i] += bsum[tile]; data[S] = grand total.
__global__ void scan_add_kernel(int* __restrict__ data, const int* __restrict__ bsum,
                                int S, int nbt) {
  int i = blockIdx.x * 256 + threadIdx.x;
  if (i < S) data[i] += bsum[blockIdx.x];
  if (i == 0) data[S] = bsum[nbt];
}

// P3: scatter edges into bucket-partitioned array, packed (src<<7)|(dst&127).
__global__ void part_kernel(const int* __restrict__ srcp, const int* __restrict__ dstp,
                            const int* __restrict__ hist, int* __restrict__ part,
                            int E, int n, int nblk, int nbuck) {
  __shared__ int cur[512];
  int t = threadIdx.x;
  for (int bb = t; bb < nbuck; bb += 256) cur[bb] = hist[bb * nblk + blockIdx.x];
  __syncthreads();
  int e0 = blockIdx.x * EPB;
  int e1 = e0 + EPB < E ? e0 + EPB : E;
  for (int i = e0 + t; i < e1; i += 256) {
    int d = dstp[i];
    if ((unsigned)d >= (unsigned)n) continue;
    int s = srcp[i];
    int pos = atomicAdd(&cur[d >> 7], 1);
    part[pos] = (s << 7) | (d & 127);
  }
}

// per-bucket degree -> dinv (no rowptr/col needed anymore)
__global__ void degv_kernel(const int* __restrict__ part, const int* __restrict__ hist,
                            float* __restrict__ dinv, int n, int nblk) {
  __shared__ int degL[NBK];
  int t = threadIdx.x;
  int b = blockIdx.x;
  if (t < NBK) degL[t] = 0;
  __syncthreads();
  int base = hist[b * nblk];
  int end = hist[(b + 1) * nblk];
  for (int i = base + t; i < end; i += 256) atomicAdd(&degL[part[i] & 127], 1);
  __syncthreads();
  if (t < NBK) {
    int node = (b << 7) + t;
    if (node < n) dinv[node] = rsqrtf((float)degL[t] + 1.0f);
  }
}

// Y[n,64] = X[n,64] @ W[64,64]; block = 4 rows x 64 cols (known-good)
__global__ void mm64_kernel(const float* __restrict__ X, const float* __restrict__ W,
                            float* __restrict__ Y, int n) {
  __shared__ float Ws[64][64];
  __shared__ float xs[4][64];
  int tid = threadIdx.x;
  for (int i = tid; i < 64 * 64; i += 256) Ws[i >> 6][i & 63] = W[i];
  int rr = tid >> 6, c = tid & 63;
  int row = blockIdx.x * 4 + rr;
  xs[rr][c] = (row < n) ? X[(size_t)row * 64 + c] : 0.0f;
  __syncthreads();
  float acc = 0.0f;
#pragma unroll
  for (int k = 0; k < 64; ++k) acc = fmaf(xs[rr][k], Ws[k][c], acc);
  if (row < n) Y[(size_t)row * 64 + c] = acc;
}

// BN affine + ELU on X rows, then @W (known-good 4-row form)
__global__ void bn_elu_mm64_kernel(const float* __restrict__ X, const float* __restrict__ W,
                                   const float* __restrict__ ss, float* __restrict__ Y, int n) {
  __shared__ float Ws[64][64];
  __shared__ float xs[4][64];
  int tid = threadIdx.x;
  for (int i = tid; i < 64 * 64; i += 256) Ws[i >> 6][i & 63] = W[i];
  int rr = tid >> 6, c = tid & 63;
  int row = blockIdx.x * 4 + rr;
  float v = 0.0f;
  if (row < n) {
    v = X[(size_t)row * 64 + c] * ss[c] + ss[64 + c];
    v = v > 0.0f ? v : expm1f(v);
  }
  xs[rr][c] = v;
  __syncthreads();
  float acc = 0.0f;
#pragma unroll
  for (int k = 0; k < 64; ++k) acc = fmaf(xs[rr][k], Ws[k][c], acc);
  if (row < n) Y[(size_t)row * 64 + c] = acc;
}

// Edge-centric accumulate: block = one 128-node dst bucket, acc in LDS.
// Stage 64 packed edges per wave (coalesced), then per edge one independent
// coalesced 256B H-row load + ds_add_f32 (fire-and-forget, no dep chain).
// Bank check: acc word addr = dl*64+lane -> bank = lane&31, 2-way = free.
__device__ __forceinline__ void edge_accumulate(
    const int* __restrict__ part, const int* __restrict__ hist,
    const float* __restrict__ dinv, const float* __restrict__ H,
    float (*acc)[64], int nblk, int b, int tid) {
  float* af = (float*)acc;
  for (int i = tid; i < NBK * 64; i += 256) af[i] = 0.0f;
  __syncthreads();
  int base = hist[b * nblk];
  int end = hist[(b + 1) * nblk];
  int wave = tid >> 6, lane = tid & 63;
  for (int i0 = base + wave * 64; i0 < end; i0 += 256) {
    int myp = i0 + lane;
    int u = (myp < end) ? part[myp] : 0;
    float w_own = (myp < end) ? dinv[u >> 7] : 0.0f;
    int m = end - i0;
    m = m < 64 ? m : 64;
#pragma unroll 4
    for (int k = 0; k < m; ++k) {
      int uk = __shfl(u, k);
      float wk = __shfl(w_own, k);
      int src = uk >> 7;
      int dl = uk & 127;
      float val = H[(size_t)src * 64 + lane] * wk;
      atomicAdd(&acc[dl][lane], val);
    }
  }
  __syncthreads();
}

// edge gather + BN-stat accumulation (256-replica scratch bnsR[256][128]).
__global__ void gather_bn_kernel(const int* __restrict__ part, const int* __restrict__ hist,
                                 const float* __restrict__ dinv, const float* __restrict__ H,
                                 const float* __restrict__ b1, float* __restrict__ OUT,
                                 float* __restrict__ bnsR, int n, int nblk) {
  __shared__ float acc[NBK][64];
  int tid = threadIdx.x;
  int b = blockIdx.x;
  edge_accumulate(part, hist, dinv, H, acc, nblk, b, tid);
  int wave = tid >> 6, lane = tid & 63;
  float bias = b1[lane];
  float s = 0.0f, s2 = 0.0f;
  int r0 = wave * 32;
  for (int r = r0; r < r0 + 32; ++r) {
    int node = (b << 7) + r;
    if (node >= n) break;
    float di = dinv[node];
    float o = fmaf(acc[r][lane], di, fmaf(H[(size_t)node * 64 + lane], di * di, bias));
    OUT[(size_t)node * 64 + lane] = o;
    s += o;
    s2 += o * o;
  }
  __shared__ float sA[4][64], sB[4][64];
  sA[wave][lane] = s;
  sB[wave][lane] = s2;
  __syncthreads();
  if (tid < 64) {
    float ts = sA[0][tid] + sA[1][tid] + sA[2][tid] + sA[3][tid];
    float ts2 = sB[0][tid] + sB[1][tid] + sB[2][tid] + sB[3][tid];
    float* d = bnsR + (size_t)(blockIdx.x & 255) * 128;
    atomicAdd(&d[tid], ts);
    atomicAdd(&d[64 + tid], ts2);
  }
}

// edge gather + pool accumulation: run-length flush on sorted batch,
// ~1-2 flushes per wave to 16-replica scratch.
__global__ void gather_pool_kernel(const int* __restrict__ part, const int* __restrict__ hist,
                                   const float* __restrict__ dinv, const float* __restrict__ H,
                                   const float* __restrict__ b2, float* __restrict__ OUT,
                                   const int* __restrict__ batch, float* __restrict__ poolR,
                                   int n, int nblk) {
  __shared__ float acc[NBK][64];
  int tid = threadIdx.x;
  int b = blockIdx.x;
  edge_accumulate(part, hist, dinv, H, acc, nblk, b, tid);
  int wave = tid >> 6, lane = tid & 63;
  float bias = b2[lane];
  float* pbase = poolR + (size_t)(blockIdx.x & 15) * 4096;
  float ps = 0.0f;
  int cur_g = -1;
  int r0 = wave * 32;
  for (int r = r0; r < r0 + 32; ++r) {
    int node = (b << 7) + r;
    if (node >= n) break;
    float di = dinv[node];
    float o = fmaf(acc[r][lane], di, fmaf(H[(size_t)node * 64 + lane], di * di, bias));
    OUT[(size_t)node * 64 + lane] = o;
    int g = batch[node];
    if (g != cur_g) {
      if (cur_g >= 0) atomicAdd(&pbase[cur_g * 64 + lane], ps);
      cur_g = ((unsigned)g < (unsigned)GGRAPHS) ? g : -1;
      ps = (cur_g >= 0) ? o : 0.0f;
    } else {
      ps += o;
    }
  }
  if (cur_g >= 0) atomicAdd(&pbase[cur_g * 64 + lane], ps);
}

// reduce 256 BN replicas -> scale/shift
__global__ void bn_final_kernel(const float* __restrict__ bnsR, const float* __restrict__ gamma,
                                const float* __restrict__ beta, float* __restrict__ ss, int n) {
  __shared__ float red[128];
  int t = threadIdx.x;  // 128 threads
  float s = 0.0f;
  for (int r = 0; r < 256; ++r) s += bnsR[r * 128 + t];
  red[t] = s;
  __syncthreads();
  if (t < 64) {
    float inv_n = 1.0f / (float)n;
    float mu = red[t] * inv_n;
    float var = red[64 + t] * inv_n - mu * mu;
    var = fmaxf(var, 0.0f);
    float sc = gamma[t] * rsqrtf(var + 1e-5f);
    ss[t] = sc;
    ss[64 + t] = beta[t] - mu * sc;
  }
}

// reduce 16 pool replicas, divide by count
__global__ void pool_final_kernel(const float* __restrict__ poolR, const int* __restrict__ cnt,
                                  float* __restrict__ out) {
  int idx = blockIdx.x * 256 + threadIdx.x;  // 4096 total
  float s = 0.0f;
  for (int r = 0; r < 16; ++r) s += poolR[r * 4096 + idx];
  int g = idx >> 6;
  float c = (float)cnt[g];
  out[idx] = s / fmaxf(c, 1.0f);
}

extern "C" void kernel_launch(void* const* d_in, const int* in_sizes, int n_in,
                              void* d_out, int out_size, void* d_ws, size_t ws_size,
                              hipStream_t stream) {
  const float* x = (const float*)d_in[0];
  const int* ei = (const int*)d_in[1];
  const int* batch = (const int*)d_in[2];
  const float* W1 = (const float*)d_in[3];
  const float* b1 = (const float*)d_in[4];
  const float* gamma = (const float*)d_in[5];
  const float* beta = (const float*)d_in[6];
  const float* W2 = (const float*)d_in[7];
  const float* b2 = (const float*)d_in[8];

  const int n = in_sizes[0] / 64;
  const int E = in_sizes[1] / 2;
  const int* srcp = ei;
  const int* dstp = ei + E;

  int nblkP = (E + EPB - 1) / EPB;    // 98 partition blocks
  int nbuck = (n + NBK - 1) / NBK;    // 391 buckets (needs n <= 65536)
  int S = nbuck * nblkP;              // 38318 counters
  int nbt = (S + 255) / 256;          // 150 scan tiles (<= 256)

  float* ws = (float*)d_ws;
  size_t nf = (size_t)n * 64;
  float* bufA = ws;                   // h1, then h2'
  float* bufB = ws + nf;              // pre-BN h
  float* dinv = ws + 2 * nf;          // n floats
  float* ss = dinv + n;               // 128
  int* part = (int*)(ss + 128);       // E packed edges (persists through gathers)
  int* hist = part + E;               // S+1
  int* bsum = hist + S + 1;           // nbt+1 (<=257)
  float* bnsR = (float*)(bsum + 257); // 256*128  (zero region starts here)
  float* poolR = bnsR + 256 * 128;    // 16*4096
  int* cnti = (int*)(poolR + 16 * 4096);  // 64   (zero region ends here)

  float* out = (float*)d_out;  // FLOAT32 output

  size_t zbytes = (size_t)((char*)(cnti + 64) - (char*)bnsR);
  hipMemsetAsync(bnsR, 0, zbytes, stream);

  int blk = 256;
  int gridRows = (n + 3) / 4;

  phist_kernel<<<nblkP, blk, 0, stream>>>(dstp, hist, E, n, nblkP, nbuck);
  cnt_kernel<<<128, blk, 0, stream>>>(batch, cnti, n);
  scan1_kernel<<<nbt, blk, 0, stream>>>(hist, hist, bsum, S);
  scan2_kernel<<<1, blk, 0, stream>>>(bsum, nbt);
  scan_add_kernel<<<nbt, blk, 0, stream>>>(hist, bsum, S, nbt);
  part_kernel<<<nblkP, blk, 0, stream>>>(srcp, dstp, hist, part, E, n, nblkP, nbuck);
  degv_kernel<<<nbuck, blk, 0, stream>>>(part, hist, dinv, n, nblkP);

  mm64_kernel<<<gridRows, blk, 0, stream>>>(x, W1, bufA, n);
  gather_bn_kernel<<<nbuck, blk, 0, stream>>>(part, hist, dinv, bufA, b1, bufB, bnsR,
                                              n, nblkP);
  bn_final_kernel<<<1, 128, 0, stream>>>(bnsR, gamma, beta, ss, n);
  bn_elu_mm64_kernel<<<gridRows, blk, 0, stream>>>(bufB, W2, ss, bufA, n);
  gather_pool_kernel<<<nbuck, blk, 0, stream>>>(part, hist, dinv, bufA, b2, out, batch,
                                                poolR, n, nblkP);
  pool_final_kernel<<<16, blk, 0, stream>>>(poolR, cnti, out + nf);
}

// Round 9
// 292.645 us; speedup vs baseline: 3.3315x; 3.3315x over previous
//
#include <hip/hip_runtime.h>

// GCNEncoder: 2x GCNConv(64->64) + BatchNorm + ELU + global_mean_pool
// N=50000, E=800000, D=64, G=64. Inputs f32/int32, output f32.
// R19 284.2 -> R23 276.2 (fused epilogues, replicated scratch) ->
// R24 276.9 neutral (ILP/wgt) -> R25 974.9 FAILED (edge-centric: 1.5k waves
//   for the whole chip, occupancy 15% -- per-wave serial edge chain).
// Gather verdict after 3 experiments: row-centric ~45us/gather is a
//   random-256B L3/fabric bandwidth floor; scheduling-invariant. Stop.
// R26: revert to R23 exactly, then consolidate launches (14 -> 11):
//   (1) cnt folded into phist (second LDS histogram, same edge blocks);
//   (2) scan1+scan2+scan_add -> single-block 1024-thread chunked scan
//       (19 items/thread serial + Hillis-Steele over 1024 partials).
//   Gathers / matmuls / csr / epilogues byte-identical to R23.

constexpr int GGRAPHS = 64;
constexpr int EPB = 8192;  // edges per partition block

// P1 + cnt: per-block bucket histogram of dst (bucket = dst>>8) AND the
// graph-size histogram of batch (grid-stride), both via LDS.
__global__ void phist_cnt_kernel(const int* __restrict__ dst, const int* __restrict__ batch,
                                 int* __restrict__ hist, int* __restrict__ cnt,
                                 int E, int n, int nblk, int nbuck) {
  __shared__ int h[256];
  __shared__ int hb[GGRAPHS];
  int t = threadIdx.x;
  h[t] = 0;
  if (t < GGRAPHS) hb[t] = 0;
  __syncthreads();
  int e0 = blockIdx.x * EPB;
  int e1 = e0 + EPB < E ? e0 + EPB : E;
  for (int i = e0 + t; i < e1; i += 256) {
    int d = dst[i];
    if ((unsigned)d < (unsigned)n) atomicAdd(&h[d >> 8], 1);
  }
  for (int i = blockIdx.x * 256 + t; i < n; i += gridDim.x * 256) {
    int g = batch[i];
    if ((unsigned)g < (unsigned)GGRAPHS) atomicAdd(&hb[g], 1);
  }
  __syncthreads();
  if (t < nbuck) hist[t * nblk + blockIdx.x] = h[t];
  if (t < GGRAPHS && hb[t] > 0) atomicAdd(&cnt[t], hb[t]);
}

// Single-block exclusive scan of hist[0..S), in place; hist[S] = total.
// 1024 threads, C items/thread: serial chunk sum -> 1024-wide Hillis-Steele
// -> serial chunk rewrite. S <= 1024*C.
__global__ void scan_all_kernel(int* __restrict__ hist, int S, int C) {
  __shared__ int tmp[1024];
  int t = threadIdx.x;
  int lo = t * C;
  int hi = lo + C < S ? lo + C : S;
  int sum = 0;
  for (int i = lo; i < hi; ++i) sum += hist[i];
  tmp[t] = sum;
  __syncthreads();
#pragma unroll
  for (int off = 1; off < 1024; off <<= 1) {
    int a = (t >= off) ? tmp[t - off] : 0;
    __syncthreads();
    tmp[t] += a;
    __syncthreads();
  }
  int run = tmp[t] - sum;  // exclusive base for this chunk
  for (int i = lo; i < hi; ++i) {
    int v = hist[i];
    hist[i] = run;
    run += v;
  }
  if (t == 1023) hist[S] = tmp[1023];
}

// P3: scatter edges into bucket-partitioned array, packed (src<<8)|(dst&255).
__global__ void part_kernel(const int* __restrict__ srcp, const int* __restrict__ dstp,
                            const int* __restrict__ hist, int* __restrict__ part,
                            int E, int n, int nblk, int nbuck) {
  __shared__ int cur[256];
  int t = threadIdx.x;
  if (t < nbuck) cur[t] = hist[t * nblk + blockIdx.x];
  __syncthreads();
  int e0 = blockIdx.x * EPB;
  int e1 = e0 + EPB < E ? e0 + EPB : E;
  for (int i = e0 + t; i < e1; i += 256) {
    int d = dstp[i];
    if ((unsigned)d >= (unsigned)n) continue;
    int s = srcp[i];
    int pos = atomicAdd(&cur[d >> 8], 1);
    part[pos] = (s << 8) | (d & 255);
  }
}

// P4: one block per bucket (256 nodes). LDS degree -> LDS scan -> rowptr/dinv
// coalesced -> col placed via LDS cursors (writes stay in 16KB segment).
__global__ void csr_kernel(const int* __restrict__ part, const int* __restrict__ hist,
                           int* __restrict__ rowptr, float* __restrict__ dinv,
                           int* __restrict__ col, int n, int nblk, int nbuck) {
  __shared__ int degL[256], scn[256], cur[256];
  int t = threadIdx.x;
  int b = blockIdx.x;
  degL[t] = 0;
  cur[t] = 0;
  __syncthreads();
  int base = hist[b * nblk];
  int end = hist[(b + 1) * nblk];  // hist[S] = total for last bucket
  for (int i = base + t; i < end; i += 256) atomicAdd(&degL[part[i] & 255], 1);
  __syncthreads();
  int dv = degL[t];
  scn[t] = dv;
  __syncthreads();
#pragma unroll
  for (int off = 1; off < 256; off <<= 1) {
    int a = (t >= off) ? scn[t - off] : 0;
    __syncthreads();
    scn[t] += a;
    __syncthreads();
  }
  int excl = scn[t] - dv;
  int node = (b << 8) + t;
  if (node < n) {
    rowptr[node] = base + excl;
    dinv[node] = rsqrtf((float)dv + 1.0f);
  }
  if (b == nbuck - 1 && t == 0) rowptr[n] = end;
  scn[t] = excl;
  __syncthreads();
  for (int i = base + t; i < end; i += 256) {
    int u = part[i];
    int d = u & 255;
    int k = atomicAdd(&cur[d], 1);
    col[base + scn[d] + k] = u >> 8;
  }
}

// Y[n,64] = X[n,64] @ W[64,64]; block = 4 rows x 64 cols (known-good)
__global__ void mm64_kernel(const float* __restrict__ X, const float* __restrict__ W,
                            float* __restrict__ Y, int n) {
  __shared__ float Ws[64][64];
  __shared__ float xs[4][64];
  int tid = threadIdx.x;
  for (int i = tid; i < 64 * 64; i += 256) Ws[i >> 6][i & 63] = W[i];
  int rr = tid >> 6, c = tid & 63;
  int row = blockIdx.x * 4 + rr;
  xs[rr][c] = (row < n) ? X[(size_t)row * 64 + c] : 0.0f;
  __syncthreads();
  float acc = 0.0f;
#pragma unroll
  for (int k = 0; k < 64; ++k) acc = fmaf(xs[rr][k], Ws[k][c], acc);
  if (row < n) Y[(size_t)row * 64 + c] = acc;
}

// BN affine + ELU on X rows, then @W (known-good 4-row form)
__global__ void bn_elu_mm64_kernel(const float* __restrict__ X, const float* __restrict__ W,
                                   const float* __restrict__ ss, float* __restrict__ Y, int n) {
  __shared__ float Ws[64][64];
  __shared__ float xs[4][64];
  int tid = threadIdx.x;
  for (int i = tid; i < 64 * 64; i += 256) Ws[i >> 6][i & 63] = W[i];
  int rr = tid >> 6, c = tid & 63;
  int row = blockIdx.x * 4 + rr;
  float v = 0.0f;
  if (row < n) {
    v = X[(size_t)row * 64 + c] * ss[c] + ss[64 + c];
    v = v > 0.0f ? v : expm1f(v);
  }
  xs[rr][c] = v;
  __syncthreads();
  float acc = 0.0f;
#pragma unroll
  for (int k = 0; k < 64; ++k) acc = fmaf(xs[rr][k], Ws[k][c], acc);
  if (row < n) Y[(size_t)row * 64 + c] = acc;
}

// Gather core: 1 wave/row, lanes = 4 neighbor-slots x 16 channel-quads.
// R18-proven inner loop: k+=4, one float4 load per iter, unroll 4.
__device__ __forceinline__ float4 gcn_gather_core(
    const int* __restrict__ rowptr, const int* __restrict__ col,
    const float* __restrict__ dinv, const float4* __restrict__ H4,
    int row, int lane, int sub, int cg, bool valid) {
  float4 acc = make_float4(0.f, 0.f, 0.f, 0.f);
  int p0 = 0, p1 = 0;
  if (valid) { p0 = rowptr[row]; p1 = rowptr[row + 1]; }
  for (int base = p0; base < p1; base += 64) {
    int myp = base + lane;
    int j = (myp < p1) ? col[myp] : 0;
    float w = (myp < p1) ? dinv[j] : 0.0f;
    int m = p1 - base;
    m = m < 64 ? m : 64;
#pragma unroll 4
    for (int k = 0; k < m; k += 4) {
      int s = k + sub;               // <= 63 always (k <= 60)
      int jj = __shfl(j, s);
      float ww = __shfl(w, s);       // 0 for tail slots past p1
      float4 hv = H4[(size_t)jj * 16 + cg];
      acc.x = fmaf(hv.x, ww, acc.x);
      acc.y = fmaf(hv.y, ww, acc.y);
      acc.z = fmaf(hv.z, ww, acc.z);
      acc.w = fmaf(hv.w, ww, acc.w);
    }
  }
  acc.x += __shfl_xor(acc.x, 16);
  acc.y += __shfl_xor(acc.y, 16);
  acc.z += __shfl_xor(acc.z, 16);
  acc.w += __shfl_xor(acc.w, 16);
  acc.x += __shfl_xor(acc.x, 32);
  acc.y += __shfl_xor(acc.y, 32);
  acc.z += __shfl_xor(acc.z, 32);
  acc.w += __shfl_xor(acc.w, 32);
  return acc;
}

// gather + BN-stat accumulation (256-replica scratch bnsR[256][128]).
__global__ void gather_bn_kernel(const int* __restrict__ rowptr, const int* __restrict__ col,
                                 const float* __restrict__ dinv, const float* __restrict__ H,
                                 const float* __restrict__ b, float* __restrict__ OUT,
                                 float* __restrict__ bnsR, int n) {
  int wave = threadIdx.x >> 6;
  int lane = threadIdx.x & 63;
  int row = blockIdx.x * 4 + wave;
  bool valid = row < n;
  int sub = lane >> 4;
  int cg = lane & 15;
  const float4* __restrict__ H4 = (const float4*)H;
  float4 acc = gcn_gather_core(rowptr, col, dinv, H4, row, lane, sub, cg, valid);
  float4 o = make_float4(0.f, 0.f, 0.f, 0.f);
  if (valid) {
    float di = dinv[row];
    float d2 = di * di;
    float4 self = H4[(size_t)row * 16 + cg];
    float4 bb = ((const float4*)b)[cg];
    o.x = fmaf(acc.x, di, fmaf(self.x, d2, bb.x));
    o.y = fmaf(acc.y, di, fmaf(self.y, d2, bb.y));
    o.z = fmaf(acc.z, di, fmaf(self.z, d2, bb.z));
    o.w = fmaf(acc.w, di, fmaf(self.w, d2, bb.w));
    if (sub == 0) ((float4*)OUT)[(size_t)row * 16 + cg] = o;
  }
  __shared__ float sA[4][64], sB[4][64];
  if (sub == 0) {
    sA[wave][4 * cg + 0] = o.x;
    sA[wave][4 * cg + 1] = o.y;
    sA[wave][4 * cg + 2] = o.z;
    sA[wave][4 * cg + 3] = o.w;
    sB[wave][4 * cg + 0] = o.x * o.x;
    sB[wave][4 * cg + 1] = o.y * o.y;
    sB[wave][4 * cg + 2] = o.z * o.z;
    sB[wave][4 * cg + 3] = o.w * o.w;
  }
  __syncthreads();
  int t = threadIdx.x;
  if (t < 64) {
    float s = sA[0][t] + sA[1][t] + sA[2][t] + sA[3][t];
    float s2 = sB[0][t] + sB[1][t] + sB[2][t] + sB[3][t];
    float* d = bnsR + (size_t)(blockIdx.x & 255) * 128;
    atomicAdd(&d[t], s);
    atomicAdd(&d[64 + t], s2);
  }
}

// gather + pool accumulation: LDS pre-reduce the block's 4 (sorted) rows,
// then 64 atomics/block to one of 16 replicas (chains ~12).
__global__ void gather_pool_kernel(const int* __restrict__ rowptr, const int* __restrict__ col,
                                   const float* __restrict__ dinv, const float* __restrict__ H,
                                   const float* __restrict__ b, float* __restrict__ OUT,
                                   const int* __restrict__ batch, float* __restrict__ poolR,
                                   int n) {
  int wave = threadIdx.x >> 6;
  int lane = threadIdx.x & 63;
  int row = blockIdx.x * 4 + wave;
  bool valid = row < n;
  int sub = lane >> 4;
  int cg = lane & 15;
  const float4* __restrict__ H4 = (const float4*)H;
  float4 acc = gcn_gather_core(rowptr, col, dinv, H4, row, lane, sub, cg, valid);
  float4 o = make_float4(0.f, 0.f, 0.f, 0.f);
  __shared__ float sO[4][64];
  __shared__ int sG[4];
  if (valid) {
    float di = dinv[row];
    float d2 = di * di;
    float4 self = H4[(size_t)row * 16 + cg];
    float4 bb = ((const float4*)b)[cg];
    o.x = fmaf(acc.x, di, fmaf(self.x, d2, bb.x));
    o.y = fmaf(acc.y, di, fmaf(self.y, d2, bb.y));
    o.z = fmaf(acc.z, di, fmaf(self.z, d2, bb.z));
    o.w = fmaf(acc.w, di, fmaf(self.w, d2, bb.w));
    if (sub == 0) ((float4*)OUT)[(size_t)row * 16 + cg] = o;
  }
  if (lane == 0) {
    int g = valid ? batch[row] : -1;
    sG[wave] = ((unsigned)g < (unsigned)GGRAPHS) ? g : -1;
  }
  if (sub == 0) {
    sO[wave][4 * cg + 0] = o.x;
    sO[wave][4 * cg + 1] = o.y;
    sO[wave][4 * cg + 2] = o.z;
    sO[wave][4 * cg + 3] = o.w;
  }
  __syncthreads();
  int t = threadIdx.x;
  if (t < 64) {
    float* base = poolR + (size_t)(blockIdx.x & 15) * 4096;
    int g0 = sG[0];
    float s0 = 0.0f;
#pragma unroll
    for (int w = 0; w < 4; ++w) {
      int gw = sG[w];
      if (gw < 0) continue;
      if (gw == g0) s0 += sO[w][t];
      else atomicAdd(&base[gw * 64 + t], sO[w][t]);  // rare: graph boundary
    }
    if (g0 >= 0) atomicAdd(&base[g0 * 64 + t], s0);
  }
}

// reduce 256 BN replicas -> scale/shift
__global__ void bn_final_kernel(const float* __restrict__ bnsR, const float* __restrict__ gamma,
                                const float* __restrict__ beta, float* __restrict__ ss, int n) {
  __shared__ float red[128];
  int t = threadIdx.x;  // 128 threads
  float s = 0.0f;
  for (int r = 0; r < 256; ++r) s += bnsR[r * 128 + t];
  red[t] = s;
  __syncthreads();
  if (t < 64) {
    float inv_n = 1.0f / (float)n;
    float mu = red[t] * inv_n;
    float var = red[64 + t] * inv_n - mu * mu;
    var = fmaxf(var, 0.0f);
    float sc = gamma[t] * rsqrtf(var + 1e-5f);
    ss[t] = sc;
    ss[64 + t] = beta[t] - mu * sc;
  }
}

// reduce 16 pool replicas, divide by count
__global__ void pool_final_kernel(const float* __restrict__ poolR, const int* __restrict__ cnt,
                                  float* __restrict__ out) {
  int idx = blockIdx.x * 256 + threadIdx.x;  // 4096 total
  float s = 0.0f;
  for (int r = 0; r < 16; ++r) s += poolR[r * 4096 + idx];
  int g = idx >> 6;
  float c = (float)cnt[g];
  out[idx] = s / fmaxf(c, 1.0f);
}

extern "C" void kernel_launch(void* const* d_in, const int* in_sizes, int n_in,
                              void* d_out, int out_size, void* d_ws, size_t ws_size,
                              hipStream_t stream) {
  const float* x = (const float*)d_in[0];
  const int* ei = (const int*)d_in[1];
  const int* batch = (const int*)d_in[2];
  const float* W1 = (const float*)d_in[3];
  const float* b1 = (const float*)d_in[4];
  const float* gamma = (const float*)d_in[5];
  const float* beta = (const float*)d_in[6];
  const float* W2 = (const float*)d_in[7];
  const float* b2 = (const float*)d_in[8];

  const int n = in_sizes[0] / 64;
  const int E = in_sizes[1] / 2;
  const int* srcp = ei;
  const int* dstp = ei + E;

  float* ws = (float*)d_ws;
  size_t nf = (size_t)n * 64;
  float* bufA = ws;                   // h1, then h2' (aliases part/hist in preproc)
  float* bufB = ws + nf;              // pre-BN h
  float* dinv = ws + 2 * nf;          // n floats
  float* ss = dinv + n;               // 128
  int* rowptr = (int*)(ss + 128);     // n+1
  int* col = rowptr + n + 1;          // E
  float* bnsR = (float*)(col + E);    // 256*128  (zero region starts here)
  float* poolR = bnsR + 256 * 128;    // 16*4096
  int* cnti = (int*)(poolR + 16 * 4096);  // 64   (zero region ends here)

  // preprocessing scratch aliased into bufA (free until mm64)
  int* part = (int*)bufA;             // E packed edges
  int* hist = part + E;               // S+1

  float* out = (float*)d_out;  // FLOAT32 output

  size_t zbytes = (size_t)((char*)(cnti + 64) - (char*)bnsR);
  hipMemsetAsync(bnsR, 0, zbytes, stream);

  int blk = 256;
  int nblkP = (E + EPB - 1) / EPB;    // 98 partition blocks
  int nbuck = (n + 255) >> 8;         // 196 buckets (needs n <= 65536)
  int S = nbuck * nblkP;              // 19208 counters
  int C = (S + 1023) / 1024;          // items per scan thread (19)
  int gridRows = (n + 3) / 4;

  phist_cnt_kernel<<<nblkP, blk, 0, stream>>>(dstp, batch, hist, cnti, E, n, nblkP, nbuck);
  scan_all_kernel<<<1, 1024, 0, stream>>>(hist, S, C);
  part_kernel<<<nblkP, blk, 0, stream>>>(srcp, dstp, hist, part, E, n, nblkP, nbuck);
  csr_kernel<<<nbuck, blk, 0, stream>>>(part, hist, rowptr, dinv, col, n, nblkP, nbuck);

  mm64_kernel<<<gridRows, blk, 0, stream>>>(x, W1, bufA, n);
  gather_bn_kernel<<<gridRows, blk, 0, stream>>>(rowptr, col, dinv, bufA, b1, bufB, bnsR, n);
  bn_final_kernel<<<1, 128, 0, stream>>>(bnsR, gamma, beta, ss, n);
  bn_elu_mm64_kernel<<<gridRows, blk, 0, stream>>>(bufB, W2, ss, bufA, n);
  gather_pool_kernel<<<gridRows, blk, 0, stream>>>(rowptr, col, dinv, bufA, b2, out, batch,
                                                   poolR, n);
  pool_final_kernel<<<16, blk, 0, stream>>>(poolR, cnti, out + nf);
}

// Round 10
// 267.033 us; speedup vs baseline: 3.6510x; 1.0959x over previous
//
#include <hip/hip_runtime.h>

// GCNEncoder: 2x GCNConv(64->64) + BatchNorm + ELU + global_mean_pool
// N=50000, E=800000, D=64, G=64. Inputs f32/int32, output f32.
// R19 284.2 -> R23 276.2 (fused epilogues, replicated scratch) = BEST.
// R24 neutral; R25 974.9 FAILED (edge-centric, occupancy collapse);
// R26 292.6 REGRESSED (single-block scan serialized the chain).
// R27: exact R23 kernels, but exploit the DEPENDENCY GRAPH: mm64 (x@W1)
//   is independent of the CSR build, so fuse {phist, cnt, mm64} into one
//   fat kernel via disjoint blockIdx ranges (preproc blocks first ->
//   dispatched immediately; mm64's 12.5k blocks fill the machine behind).
//   Hides phist+cnt under mm64, kills 2 launch gaps. part/hist get their
//   own region (no bufA aliasing -- mm64 writes h1 before part runs now).
//   Scan restored to R23's verified 3-kernel form.

constexpr int GGRAPHS = 64;
constexpr int EPB = 8192;  // edges per partition block
constexpr int CNTB = 128;  // blocks for cnt histogram

// Fat kernel: [0,nblkP) = phist blocks; [nblkP,nblkP+CNTB) = cnt blocks;
// [nblkP+CNTB, ...) = mm64 blocks. Bodies identical to R23 standalones.
__global__ void fat_phist_cnt_mm64_kernel(
    const int* __restrict__ dst, const int* __restrict__ batch,
    int* __restrict__ hist, int* __restrict__ cnt,
    const float* __restrict__ X, const float* __restrict__ W,
    float* __restrict__ Y,
    int E, int n, int nblk, int nbuck) {
  __shared__ float Ws[64][64];
  __shared__ float xs[4][64];
  __shared__ int h[256];
  __shared__ int hb[GGRAPHS];
  int t = threadIdx.x;
  int bid = blockIdx.x;
  if (bid < nblk) {
    // ---- phist body ----
    h[t] = 0;
    __syncthreads();
    int e0 = bid * EPB;
    int e1 = e0 + EPB < E ? e0 + EPB : E;
    for (int i = e0 + t; i < e1; i += 256) {
      int d = dst[i];
      if ((unsigned)d < (unsigned)n) atomicAdd(&h[d >> 8], 1);
    }
    __syncthreads();
    if (t < nbuck) hist[t * nblk + bid] = h[t];
  } else if (bid < nblk + CNTB) {
    // ---- cnt body ----
    int cb = bid - nblk;
    if (t < GGRAPHS) hb[t] = 0;
    __syncthreads();
    for (int i = cb * 256 + t; i < n; i += CNTB * 256) {
      int g = batch[i];
      if ((unsigned)g < (unsigned)GGRAPHS) atomicAdd(&hb[g], 1);
    }
    __syncthreads();
    if (t < GGRAPHS && hb[t] > 0) atomicAdd(&cnt[t], hb[t]);
  } else {
    // ---- mm64 body (4 rows x 64 cols) ----
    int mb = bid - nblk - CNTB;
    for (int i = t; i < 64 * 64; i += 256) Ws[i >> 6][i & 63] = W[i];
    int rr = t >> 6, c = t & 63;
    int row = mb * 4 + rr;
    xs[rr][c] = (row < n) ? X[(size_t)row * 64 + c] : 0.0f;
    __syncthreads();
    float acc = 0.0f;
#pragma unroll
    for (int k = 0; k < 64; ++k) acc = fmaf(xs[rr][k], Ws[k][c], acc);
    if (row < n) Y[(size_t)row * 64 + c] = acc;
  }
}

// scan pass 1: per-256-tile exclusive scan; out[i]=local excl, bsum[b]=tile total.
__global__ void scan1_kernel(const int* __restrict__ in, int* __restrict__ out,
                             int* __restrict__ bsum, int n) {
  __shared__ int tmp[256];
  int t = threadIdx.x;
  int i = blockIdx.x * 256 + t;
  int v = (i < n) ? in[i] : 0;
  tmp[t] = v;
  __syncthreads();
#pragma unroll
  for (int off = 1; off < 256; off <<= 1) {
    int a = (t >= off) ? tmp[t - off] : 0;
    __syncthreads();
    tmp[t] += a;
    __syncthreads();
  }
  if (i < n) out[i] = tmp[t] - v;  // exclusive
  if (t == 255) bsum[blockIdx.x] = tmp[255];
}

// scan pass 2: 1 block, exclusive scan of bsum[nb] (nb <= 256); bsum[nb] = total.
__global__ void scan2_kernel(int* __restrict__ bsum, int nb) {
  __shared__ int tmp[256];
  int t = threadIdx.x;
  int v = (t < nb) ? bsum[t] : 0;
  tmp[t] = v;
  __syncthreads();
#pragma unroll
  for (int off = 1; off < 256; off <<= 1) {
    int a = (t >= off) ? tmp[t - off] : 0;
    __syncthreads();
    tmp[t] += a;
    __syncthreads();
  }
  if (t < nb) bsum[t] = tmp[t] - v;
  if (t == 255) bsum[nb] = tmp[255];
}

// scan pass 3: data[i] += bsum[tile]; data[S] = grand total.
__global__ void scan_add_kernel(int* __restrict__ data, const int* __restrict__ bsum,
                                int S, int nbt) {
  int i = blockIdx.x * 256 + threadIdx.x;
  if (i < S) data[i] += bsum[blockIdx.x];
  if (i == 0) data[S] = bsum[nbt];
}

// P3: scatter edges into bucket-partitioned array, packed (src<<8)|(dst&255).
__global__ void part_kernel(const int* __restrict__ srcp, const int* __restrict__ dstp,
                            const int* __restrict__ hist, int* __restrict__ part,
                            int E, int n, int nblk, int nbuck) {
  __shared__ int cur[256];
  int t = threadIdx.x;
  if (t < nbuck) cur[t] = hist[t * nblk + blockIdx.x];
  __syncthreads();
  int e0 = blockIdx.x * EPB;
  int e1 = e0 + EPB < E ? e0 + EPB : E;
  for (int i = e0 + t; i < e1; i += 256) {
    int d = dstp[i];
    if ((unsigned)d >= (unsigned)n) continue;
    int s = srcp[i];
    int pos = atomicAdd(&cur[d >> 8], 1);
    part[pos] = (s << 8) | (d & 255);
  }
}

// P4: one block per bucket (256 nodes). LDS degree -> LDS scan -> rowptr/dinv
// coalesced -> col placed via LDS cursors (writes stay in 16KB segment).
__global__ void csr_kernel(const int* __restrict__ part, const int* __restrict__ hist,
                           int* __restrict__ rowptr, float* __restrict__ dinv,
                           int* __restrict__ col, int n, int nblk, int nbuck) {
  __shared__ int degL[256], scn[256], cur[256];
  int t = threadIdx.x;
  int b = blockIdx.x;
  degL[t] = 0;
  cur[t] = 0;
  __syncthreads();
  int base = hist[b * nblk];
  int end = hist[(b + 1) * nblk];  // hist[S] = total for last bucket
  for (int i = base + t; i < end; i += 256) atomicAdd(&degL[part[i] & 255], 1);
  __syncthreads();
  int dv = degL[t];
  scn[t] = dv;
  __syncthreads();
#pragma unroll
  for (int off = 1; off < 256; off <<= 1) {
    int a = (t >= off) ? scn[t - off] : 0;
    __syncthreads();
    scn[t] += a;
    __syncthreads();
  }
  int excl = scn[t] - dv;
  int node = (b << 8) + t;
  if (node < n) {
    rowptr[node] = base + excl;
    dinv[node] = rsqrtf((float)dv + 1.0f);
  }
  if (b == nbuck - 1 && t == 0) rowptr[n] = end;
  scn[t] = excl;
  __syncthreads();
  for (int i = base + t; i < end; i += 256) {
    int u = part[i];
    int d = u & 255;
    int k = atomicAdd(&cur[d], 1);
    col[base + scn[d] + k] = u >> 8;
  }
}

// BN affine + ELU on X rows, then @W (known-good 4-row form)
__global__ void bn_elu_mm64_kernel(const float* __restrict__ X, const float* __restrict__ W,
                                   const float* __restrict__ ss, float* __restrict__ Y, int n) {
  __shared__ float Ws[64][64];
  __shared__ float xs[4][64];
  int tid = threadIdx.x;
  for (int i = tid; i < 64 * 64; i += 256) Ws[i >> 6][i & 63] = W[i];
  int rr = tid >> 6, c = tid & 63;
  int row = blockIdx.x * 4 + rr;
  float v = 0.0f;
  if (row < n) {
    v = X[(size_t)row * 64 + c] * ss[c] + ss[64 + c];
    v = v > 0.0f ? v : expm1f(v);
  }
  xs[rr][c] = v;
  __syncthreads();
  float acc = 0.0f;
#pragma unroll
  for (int k = 0; k < 64; ++k) acc = fmaf(xs[rr][k], Ws[k][c], acc);
  if (row < n) Y[(size_t)row * 64 + c] = acc;
}

// Gather core: 1 wave/row, lanes = 4 neighbor-slots x 16 channel-quads.
// R18-proven inner loop: k+=4, one float4 load per iter, unroll 4.
__device__ __forceinline__ float4 gcn_gather_core(
    const int* __restrict__ rowptr, const int* __restrict__ col,
    const float* __restrict__ dinv, const float4* __restrict__ H4,
    int row, int lane, int sub, int cg, bool valid) {
  float4 acc = make_float4(0.f, 0.f, 0.f, 0.f);
  int p0 = 0, p1 = 0;
  if (valid) { p0 = rowptr[row]; p1 = rowptr[row + 1]; }
  for (int base = p0; base < p1; base += 64) {
    int myp = base + lane;
    int j = (myp < p1) ? col[myp] : 0;
    float w = (myp < p1) ? dinv[j] : 0.0f;
    int m = p1 - base;
    m = m < 64 ? m : 64;
#pragma unroll 4
    for (int k = 0; k < m; k += 4) {
      int s = k + sub;               // <= 63 always (k <= 60)
      int jj = __shfl(j, s);
      float ww = __shfl(w, s);       // 0 for tail slots past p1
      float4 hv = H4[(size_t)jj * 16 + cg];
      acc.x = fmaf(hv.x, ww, acc.x);
      acc.y = fmaf(hv.y, ww, acc.y);
      acc.z = fmaf(hv.z, ww, acc.z);
      acc.w = fmaf(hv.w, ww, acc.w);
    }
  }
  acc.x += __shfl_xor(acc.x, 16);
  acc.y += __shfl_xor(acc.y, 16);
  acc.z += __shfl_xor(acc.z, 16);
  acc.w += __shfl_xor(acc.w, 16);
  acc.x += __shfl_xor(acc.x, 32);
  acc.y += __shfl_xor(acc.y, 32);
  acc.z += __shfl_xor(acc.z, 32);
  acc.w += __shfl_xor(acc.w, 32);
  return acc;
}

// gather + BN-stat accumulation (256-replica scratch bnsR[256][128]).
__global__ void gather_bn_kernel(const int* __restrict__ rowptr, const int* __restrict__ col,
                                 const float* __restrict__ dinv, const float* __restrict__ H,
                                 const float* __restrict__ b, float* __restrict__ OUT,
                                 float* __restrict__ bnsR, int n) {
  int wave = threadIdx.x >> 6;
  int lane = threadIdx.x & 63;
  int row = blockIdx.x * 4 + wave;
  bool valid = row < n;
  int sub = lane >> 4;
  int cg = lane & 15;
  const float4* __restrict__ H4 = (const float4*)H;
  float4 acc = gcn_gather_core(rowptr, col, dinv, H4, row, lane, sub, cg, valid);
  float4 o = make_float4(0.f, 0.f, 0.f, 0.f);
  if (valid) {
    float di = dinv[row];
    float d2 = di * di;
    float4 self = H4[(size_t)row * 16 + cg];
    float4 bb = ((const float4*)b)[cg];
    o.x = fmaf(acc.x, di, fmaf(self.x, d2, bb.x));
    o.y = fmaf(acc.y, di, fmaf(self.y, d2, bb.y));
    o.z = fmaf(acc.z, di, fmaf(self.z, d2, bb.z));
    o.w = fmaf(acc.w, di, fmaf(self.w, d2, bb.w));
    if (sub == 0) ((float4*)OUT)[(size_t)row * 16 + cg] = o;
  }
  __shared__ float sA[4][64], sB[4][64];
  if (sub == 0) {
    sA[wave][4 * cg + 0] = o.x;
    sA[wave][4 * cg + 1] = o.y;
    sA[wave][4 * cg + 2] = o.z;
    sA[wave][4 * cg + 3] = o.w;
    sB[wave][4 * cg + 0] = o.x * o.x;
    sB[wave][4 * cg + 1] = o.y * o.y;
    sB[wave][4 * cg + 2] = o.z * o.z;
    sB[wave][4 * cg + 3] = o.w * o.w;
  }
  __syncthreads();
  int t = threadIdx.x;
  if (t < 64) {
    float s = sA[0][t] + sA[1][t] + sA[2][t] + sA[3][t];
    float s2 = sB[0][t] + sB[1][t] + sB[2][t] + sB[3][t];
    float* d = bnsR + (size_t)(blockIdx.x & 255) * 128;
    atomicAdd(&d[t], s);
    atomicAdd(&d[64 + t], s2);
  }
}

// gather + pool accumulation: LDS pre-reduce the block's 4 (sorted) rows,
// then 64 atomics/block to one of 16 replicas (chains ~12).
__global__ void gather_pool_kernel(const int* __restrict__ rowptr, const int* __restrict__ col,
                                   const float* __restrict__ dinv, const float* __restrict__ H,
                                   const float* __restrict__ b, float* __restrict__ OUT,
                                   const int* __restrict__ batch, float* __restrict__ poolR,
                                   int n) {
  int wave = threadIdx.x >> 6;
  int lane = threadIdx.x & 63;
  int row = blockIdx.x * 4 + wave;
  bool valid = row < n;
  int sub = lane >> 4;
  int cg = lane & 15;
  const float4* __restrict__ H4 = (const float4*)H;
  float4 acc = gcn_gather_core(rowptr, col, dinv, H4, row, lane, sub, cg, valid);
  float4 o = make_float4(0.f, 0.f, 0.f, 0.f);
  __shared__ float sO[4][64];
  __shared__ int sG[4];
  if (valid) {
    float di = dinv[row];
    float d2 = di * di;
    float4 self = H4[(size_t)row * 16 + cg];
    float4 bb = ((const float4*)b)[cg];
    o.x = fmaf(acc.x, di, fmaf(self.x, d2, bb.x));
    o.y = fmaf(acc.y, di, fmaf(self.y, d2, bb.y));
    o.z = fmaf(acc.z, di, fmaf(self.z, d2, bb.z));
    o.w = fmaf(acc.w, di, fmaf(self.w, d2, bb.w));
    if (sub == 0) ((float4*)OUT)[(size_t)row * 16 + cg] = o;
  }
  if (lane == 0) {
    int g = valid ? batch[row] : -1;
    sG[wave] = ((unsigned)g < (unsigned)GGRAPHS) ? g : -1;
  }
  if (sub == 0) {
    sO[wave][4 * cg + 0] = o.x;
    sO[wave][4 * cg + 1] = o.y;
    sO[wave][4 * cg + 2] = o.z;
    sO[wave][4 * cg + 3] = o.w;
  }
  __syncthreads();
  int t = threadIdx.x;
  if (t < 64) {
    float* base = poolR + (size_t)(blockIdx.x & 15) * 4096;
    int g0 = sG[0];
    float s0 = 0.0f;
#pragma unroll
    for (int w = 0; w < 4; ++w) {
      int gw = sG[w];
      if (gw < 0) continue;
      if (gw == g0) s0 += sO[w][t];
      else atomicAdd(&base[gw * 64 + t], sO[w][t]);  // rare: graph boundary
    }
    if (g0 >= 0) atomicAdd(&base[g0 * 64 + t], s0);
  }
}

// reduce 256 BN replicas -> scale/shift
__global__ void bn_final_kernel(const float* __restrict__ bnsR, const float* __restrict__ gamma,
                                const float* __restrict__ beta, float* __restrict__ ss, int n) {
  __shared__ float red[128];
  int t = threadIdx.x;  // 128 threads
  float s = 0.0f;
  for (int r = 0; r < 256; ++r) s += bnsR[r * 128 + t];
  red[t] = s;
  __syncthreads();
  if (t < 64) {
    float inv_n = 1.0f / (float)n;
    float mu = red[t] * inv_n;
    float var = red[64 + t] * inv_n - mu * mu;
    var = fmaxf(var, 0.0f);
    float sc = gamma[t] * rsqrtf(var + 1e-5f);
    ss[t] = sc;
    ss[64 + t] = beta[t] - mu * sc;
  }
}

// reduce 16 pool replicas, divide by count
__global__ void pool_final_kernel(const float* __restrict__ poolR, const int* __restrict__ cnt,
                                  float* __restrict__ out) {
  int idx = blockIdx.x * 256 + threadIdx.x;  // 4096 total
  float s = 0.0f;
  for (int r = 0; r < 16; ++r) s += poolR[r * 4096 + idx];
  int g = idx >> 6;
  float c = (float)cnt[g];
  out[idx] = s / fmaxf(c, 1.0f);
}

extern "C" void kernel_launch(void* const* d_in, const int* in_sizes, int n_in,
                              void* d_out, int out_size, void* d_ws, size_t ws_size,
                              hipStream_t stream) {
  const float* x = (const float*)d_in[0];
  const int* ei = (const int*)d_in[1];
  const int* batch = (const int*)d_in[2];
  const float* W1 = (const float*)d_in[3];
  const float* b1 = (const float*)d_in[4];
  const float* gamma = (const float*)d_in[5];
  const float* beta = (const float*)d_in[6];
  const float* W2 = (const float*)d_in[7];
  const float* b2 = (const float*)d_in[8];

  const int n = in_sizes[0] / 64;
  const int E = in_sizes[1] / 2;
  const int* srcp = ei;
  const int* dstp = ei + E;

  int nblkP = (E + EPB - 1) / EPB;    // 98 partition blocks
  int nbuck = (n + 255) >> 8;         // 196 buckets (needs n <= 65536)
  int S = nbuck * nblkP;              // 19208 counters
  int nbt = (S + 255) / 256;          // 76 scan tiles (<= 256)
  int gridRows = (n + 3) / 4;

  float* ws = (float*)d_ws;
  size_t nf = (size_t)n * 64;
  float* bufA = ws;                   // h1, then h2'
  float* bufB = ws + nf;              // pre-BN h
  float* dinv = ws + 2 * nf;          // n floats
  float* ss = dinv + n;               // 128
  int* rowptr = (int*)(ss + 128);     // n+1
  int* col = rowptr + n + 1;          // E
  int* part = col + E;                // E (own region: bufA is live during preproc now)
  int* hist = part + E;               // S+1
  int* bsum = hist + S + 1;           // nbt+1 (<=257)
  float* bnsR = (float*)(bsum + 257); // 256*128  (zero region starts here)
  float* poolR = bnsR + 256 * 128;    // 16*4096
  int* cnti = (int*)(poolR + 16 * 4096);  // 64   (zero region ends here)

  float* out = (float*)d_out;  // FLOAT32 output

  size_t zbytes = (size_t)((char*)(cnti + 64) - (char*)bnsR);
  hipMemsetAsync(bnsR, 0, zbytes, stream);

  int blk = 256;
  int fatGrid = nblkP + CNTB + gridRows;

  fat_phist_cnt_mm64_kernel<<<fatGrid, blk, 0, stream>>>(
      dstp, batch, hist, cnti, x, W1, bufA, E, n, nblkP, nbuck);
  scan1_kernel<<<nbt, blk, 0, stream>>>(hist, hist, bsum, S);
  scan2_kernel<<<1, blk, 0, stream>>>(bsum, nbt);
  scan_add_kernel<<<nbt, blk, 0, stream>>>(hist, bsum, S, nbt);
  part_kernel<<<nblkP, blk, 0, stream>>>(srcp, dstp, hist, part, E, n, nblkP, nbuck);
  csr_kernel<<<nbuck, blk, 0, stream>>>(part, hist, rowptr, dinv, col, n, nblkP, nbuck);

  gather_bn_kernel<<<gridRows, blk, 0, stream>>>(rowptr, col, dinv, bufA, b1, bufB, bnsR, n);
  bn_final_kernel<<<1, 128, 0, stream>>>(bnsR, gamma, beta, ss, n);
  bn_elu_mm64_kernel<<<gridRows, blk, 0, stream>>>(bufB, W2, ss, bufA, n);
  gather_pool_kernel<<<gridRows, blk, 0, stream>>>(rowptr, col, dinv, bufA, b2, out, batch,
                                                   poolR, n);
  pool_final_kernel<<<16, blk, 0, stream>>>(poolR, cnti, out + nf);
}

// Round 11
// 258.272 us; speedup vs baseline: 3.7748x; 1.0339x over previous
//
#include <hip/hip_runtime.h>

// GCNEncoder: 2x GCNConv(64->64) + BatchNorm + ELU + global_mean_pool
// N=50000, E=800000, D=64, G=64. Inputs f32/int32, output f32.
// R23 276.2 (fused epilogues) -> R27 267.0 BEST (fat kernel hides
//   phist+cnt under mm64 via disjoint blockIdx ranges).
// Kernel-internal levers exhausted (R24 neutral, R25/R26 failed);
// remaining cost = serial preproc chain + launch gaps.
// R28: (1) scan2 deleted -- each scan_add block redundantly LDS-scans the
//   <=151-int bsum (L2-hot) and picks its own prefix; (2) EPB 8192->4096:
//   part_kernel 98->196 blocks (was using <38% of CUs). All compute
//   kernels byte-identical to R27.

constexpr int GGRAPHS = 64;
constexpr int EPB = 4096;  // edges per partition block (196 blocks)
constexpr int CNTB = 128;  // blocks for cnt histogram

// Fat kernel: [0,nblkP) = phist blocks; [nblkP,nblkP+CNTB) = cnt blocks;
// [nblkP+CNTB, ...) = mm64 blocks. Bodies identical to R23 standalones.
__global__ void fat_phist_cnt_mm64_kernel(
    const int* __restrict__ dst, const int* __restrict__ batch,
    int* __restrict__ hist, int* __restrict__ cnt,
    const float* __restrict__ X, const float* __restrict__ W,
    float* __restrict__ Y,
    int E, int n, int nblk, int nbuck) {
  __shared__ float Ws[64][64];
  __shared__ float xs[4][64];
  __shared__ int h[256];
  __shared__ int hb[GGRAPHS];
  int t = threadIdx.x;
  int bid = blockIdx.x;
  if (bid < nblk) {
    // ---- phist body ----
    h[t] = 0;
    __syncthreads();
    int e0 = bid * EPB;
    int e1 = e0 + EPB < E ? e0 + EPB : E;
    for (int i = e0 + t; i < e1; i += 256) {
      int d = dst[i];
      if ((unsigned)d < (unsigned)n) atomicAdd(&h[d >> 8], 1);
    }
    __syncthreads();
    if (t < nbuck) hist[t * nblk + bid] = h[t];
  } else if (bid < nblk + CNTB) {
    // ---- cnt body ----
    int cb = bid - nblk;
    if (t < GGRAPHS) hb[t] = 0;
    __syncthreads();
    for (int i = cb * 256 + t; i < n; i += CNTB * 256) {
      int g = batch[i];
      if ((unsigned)g < (unsigned)GGRAPHS) atomicAdd(&hb[g], 1);
    }
    __syncthreads();
    if (t < GGRAPHS && hb[t] > 0) atomicAdd(&cnt[t], hb[t]);
  } else {
    // ---- mm64 body (4 rows x 64 cols) ----
    int mb = bid - nblk - CNTB;
    for (int i = t; i < 64 * 64; i += 256) Ws[i >> 6][i & 63] = W[i];
    int rr = t >> 6, c = t & 63;
    int row = mb * 4 + rr;
    xs[rr][c] = (row < n) ? X[(size_t)row * 64 + c] : 0.0f;
    __syncthreads();
    float acc = 0.0f;
#pragma unroll
    for (int k = 0; k < 64; ++k) acc = fmaf(xs[rr][k], Ws[k][c], acc);
    if (row < n) Y[(size_t)row * 64 + c] = acc;
  }
}

// scan pass 1: per-256-tile exclusive scan; out[i]=local excl, bsum[b]=tile total.
__global__ void scan1_kernel(const int* __restrict__ in, int* __restrict__ out,
                             int* __restrict__ bsum, int n) {
  __shared__ int tmp[256];
  int t = threadIdx.x;
  int i = blockIdx.x * 256 + t;
  int v = (i < n) ? in[i] : 0;
  tmp[t] = v;
  __syncthreads();
#pragma unroll
  for (int off = 1; off < 256; off <<= 1) {
    int a = (t >= off) ? tmp[t - off] : 0;
    __syncthreads();
    tmp[t] += a;
    __syncthreads();
  }
  if (i < n) out[i] = tmp[t] - v;  // exclusive
  if (t == 255) bsum[blockIdx.x] = tmp[255];
}

// scan pass 2+3 fused: every block redundantly LDS-scans bsum (<=256 ints,
// L2-hot), picks its own exclusive prefix, adds to its tile. data[S]=total.
__global__ void scan_add2_kernel(int* __restrict__ data, const int* __restrict__ bsum,
                                 int S, int nbt) {
  __shared__ int tmp[256];
  int t = threadIdx.x;
  int v = (t < nbt) ? bsum[t] : 0;
  tmp[t] = v;
  __syncthreads();
#pragma unroll
  for (int off = 1; off < 256; off <<= 1) {
    int a = (t >= off) ? tmp[t - off] : 0;
    __syncthreads();
    tmp[t] += a;
    __syncthreads();
  }
  // tmp = inclusive scan of bsum
  int pre = (blockIdx.x == 0) ? 0 : tmp[blockIdx.x - 1];
  int i = blockIdx.x * 256 + t;
  if (i < S) data[i] += pre;
  if (i == 0) data[S] = tmp[nbt - 1];  // grand total
}

// P3: scatter edges into bucket-partitioned array, packed (src<<8)|(dst&255).
__global__ void part_kernel(const int* __restrict__ srcp, const int* __restrict__ dstp,
                            const int* __restrict__ hist, int* __restrict__ part,
                            int E, int n, int nblk, int nbuck) {
  __shared__ int cur[256];
  int t = threadIdx.x;
  if (t < nbuck) cur[t] = hist[t * nblk + blockIdx.x];
  __syncthreads();
  int e0 = blockIdx.x * EPB;
  int e1 = e0 + EPB < E ? e0 + EPB : E;
  for (int i = e0 + t; i < e1; i += 256) {
    int d = dstp[i];
    if ((unsigned)d >= (unsigned)n) continue;
    int s = srcp[i];
    int pos = atomicAdd(&cur[d >> 8], 1);
    part[pos] = (s << 8) | (d & 255);
  }
}

// P4: one block per bucket (256 nodes). LDS degree -> LDS scan -> rowptr/dinv
// coalesced -> col placed via LDS cursors (writes stay in 16KB segment).
__global__ void csr_kernel(const int* __restrict__ part, const int* __restrict__ hist,
                           int* __restrict__ rowptr, float* __restrict__ dinv,
                           int* __restrict__ col, int n, int nblk, int nbuck) {
  __shared__ int degL[256], scn[256], cur[256];
  int t = threadIdx.x;
  int b = blockIdx.x;
  degL[t] = 0;
  cur[t] = 0;
  __syncthreads();
  int base = hist[b * nblk];
  int end = hist[(b + 1) * nblk];  // hist[S] = total for last bucket
  for (int i = base + t; i < end; i += 256) atomicAdd(&degL[part[i] & 255], 1);
  __syncthreads();
  int dv = degL[t];
  scn[t] = dv;
  __syncthreads();
#pragma unroll
  for (int off = 1; off < 256; off <<= 1) {
    int a = (t >= off) ? scn[t - off] : 0;
    __syncthreads();
    scn[t] += a;
    __syncthreads();
  }
  int excl = scn[t] - dv;
  int node = (b << 8) + t;
  if (node < n) {
    rowptr[node] = base + excl;
    dinv[node] = rsqrtf((float)dv + 1.0f);
  }
  if (b == nbuck - 1 && t == 0) rowptr[n] = end;
  scn[t] = excl;
  __syncthreads();
  for (int i = base + t; i < end; i += 256) {
    int u = part[i];
    int d = u & 255;
    int k = atomicAdd(&cur[d], 1);
    col[base + scn[d] + k] = u >> 8;
  }
}

// BN affine + ELU on X rows, then @W (known-good 4-row form)
__global__ void bn_elu_mm64_kernel(const float* __restrict__ X, const float* __restrict__ W,
                                   const float* __restrict__ ss, float* __restrict__ Y, int n) {
  __shared__ float Ws[64][64];
  __shared__ float xs[4][64];
  int tid = threadIdx.x;
  for (int i = tid; i < 64 * 64; i += 256) Ws[i >> 6][i & 63] = W[i];
  int rr = tid >> 6, c = tid & 63;
  int row = blockIdx.x * 4 + rr;
  float v = 0.0f;
  if (row < n) {
    v = X[(size_t)row * 64 + c] * ss[c] + ss[64 + c];
    v = v > 0.0f ? v : expm1f(v);
  }
  xs[rr][c] = v;
  __syncthreads();
  float acc = 0.0f;
#pragma unroll
  for (int k = 0; k < 64; ++k) acc = fmaf(xs[rr][k], Ws[k][c], acc);
  if (row < n) Y[(size_t)row * 64 + c] = acc;
}

// Gather core: 1 wave/row, lanes = 4 neighbor-slots x 16 channel-quads.
// R18-proven inner loop: k+=4, one float4 load per iter, unroll 4.
__device__ __forceinline__ float4 gcn_gather_core(
    const int* __restrict__ rowptr, const int* __restrict__ col,
    const float* __restrict__ dinv, const float4* __restrict__ H4,
    int row, int lane, int sub, int cg, bool valid) {
  float4 acc = make_float4(0.f, 0.f, 0.f, 0.f);
  int p0 = 0, p1 = 0;
  if (valid) { p0 = rowptr[row]; p1 = rowptr[row + 1]; }
  for (int base = p0; base < p1; base += 64) {
    int myp = base + lane;
    int j = (myp < p1) ? col[myp] : 0;
    float w = (myp < p1) ? dinv[j] : 0.0f;
    int m = p1 - base;
    m = m < 64 ? m : 64;
#pragma unroll 4
    for (int k = 0; k < m; k += 4) {
      int s = k + sub;               // <= 63 always (k <= 60)
      int jj = __shfl(j, s);
      float ww = __shfl(w, s);       // 0 for tail slots past p1
      float4 hv = H4[(size_t)jj * 16 + cg];
      acc.x = fmaf(hv.x, ww, acc.x);
      acc.y = fmaf(hv.y, ww, acc.y);
      acc.z = fmaf(hv.z, ww, acc.z);
      acc.w = fmaf(hv.w, ww, acc.w);
    }
  }
  acc.x += __shfl_xor(acc.x, 16);
  acc.y += __shfl_xor(acc.y, 16);
  acc.z += __shfl_xor(acc.z, 16);
  acc.w += __shfl_xor(acc.w, 16);
  acc.x += __shfl_xor(acc.x, 32);
  acc.y += __shfl_xor(acc.y, 32);
  acc.z += __shfl_xor(acc.z, 32);
  acc.w += __shfl_xor(acc.w, 32);
  return acc;
}

// gather + BN-stat accumulation (256-replica scratch bnsR[256][128]).
__global__ void gather_bn_kernel(const int* __restrict__ rowptr, const int* __restrict__ col,
                                 const float* __restrict__ dinv, const float* __restrict__ H,
                                 const float* __restrict__ b, float* __restrict__ OUT,
                                 float* __restrict__ bnsR, int n) {
  int wave = threadIdx.x >> 6;
  int lane = threadIdx.x & 63;
  int row = blockIdx.x * 4 + wave;
  bool valid = row < n;
  int sub = lane >> 4;
  int cg = lane & 15;
  const float4* __restrict__ H4 = (const float4*)H;
  float4 acc = gcn_gather_core(rowptr, col, dinv, H4, row, lane, sub, cg, valid);
  float4 o = make_float4(0.f, 0.f, 0.f, 0.f);
  if (valid) {
    float di = dinv[row];
    float d2 = di * di;
    float4 self = H4[(size_t)row * 16 + cg];
    float4 bb = ((const float4*)b)[cg];
    o.x = fmaf(acc.x, di, fmaf(self.x, d2, bb.x));
    o.y = fmaf(acc.y, di, fmaf(self.y, d2, bb.y));
    o.z = fmaf(acc.z, di, fmaf(self.z, d2, bb.z));
    o.w = fmaf(acc.w, di, fmaf(self.w, d2, bb.w));
    if (sub == 0) ((float4*)OUT)[(size_t)row * 16 + cg] = o;
  }
  __shared__ float sA[4][64], sB[4][64];
  if (sub == 0) {
    sA[wave][4 * cg + 0] = o.x;
    sA[wave][4 * cg + 1] = o.y;
    sA[wave][4 * cg + 2] = o.z;
    sA[wave][4 * cg + 3] = o.w;
    sB[wave][4 * cg + 0] = o.x * o.x;
    sB[wave][4 * cg + 1] = o.y * o.y;
    sB[wave][4 * cg + 2] = o.z * o.z;
    sB[wave][4 * cg + 3] = o.w * o.w;
  }
  __syncthreads();
  int t = threadIdx.x;
  if (t < 64) {
    float s = sA[0][t] + sA[1][t] + sA[2][t] + sA[3][t];
    float s2 = sB[0][t] + sB[1][t] + sB[2][t] + sB[3][t];
    float* d = bnsR + (size_t)(blockIdx.x & 255) * 128;
    atomicAdd(&d[t], s);
    atomicAdd(&d[64 + t], s2);
  }
}

// gather + pool accumulation: LDS pre-reduce the block's 4 (sorted) rows,
// then 64 atomics/block to one of 16 replicas (chains ~12).
__global__ void gather_pool_kernel(const int* __restrict__ rowptr, const int* __restrict__ col,
                                   const float* __restrict__ dinv, const float* __restrict__ H,
                                   const float* __restrict__ b, float* __restrict__ OUT,
                                   const int* __restrict__ batch, float* __restrict__ poolR,
                                   int n) {
  int wave = threadIdx.x >> 6;
  int lane = threadIdx.x & 63;
  int row = blockIdx.x * 4 + wave;
  bool valid = row < n;
  int sub = lane >> 4;
  int cg = lane & 15;
  const float4* __restrict__ H4 = (const float4*)H;
  float4 acc = gcn_gather_core(rowptr, col, dinv, H4, row, lane, sub, cg, valid);
  float4 o = make_float4(0.f, 0.f, 0.f, 0.f);
  __shared__ float sO[4][64];
  __shared__ int sG[4];
  if (valid) {
    float di = dinv[row];
    float d2 = di * di;
    float4 self = H4[(size_t)row * 16 + cg];
    float4 bb = ((const float4*)b)[cg];
    o.x = fmaf(acc.x, di, fmaf(self.x, d2, bb.x));
    o.y = fmaf(acc.y, di, fmaf(self.y, d2, bb.y));
    o.z = fmaf(acc.z, di, fmaf(self.z, d2, bb.z));
    o.w = fmaf(acc.w, di, fmaf(self.w, d2, bb.w));
    if (sub == 0) ((float4*)OUT)[(size_t)row * 16 + cg] = o;
  }
  if (lane == 0) {
    int g = valid ? batch[row] : -1;
    sG[wave] = ((unsigned)g < (unsigned)GGRAPHS) ? g : -1;
  }
  if (sub == 0) {
    sO[wave][4 * cg + 0] = o.x;
    sO[wave][4 * cg + 1] = o.y;
    sO[wave][4 * cg + 2] = o.z;
    sO[wave][4 * cg + 3] = o.w;
  }
  __syncthreads();
  int t = threadIdx.x;
  if (t < 64) {
    float* base = poolR + (size_t)(blockIdx.x & 15) * 4096;
    int g0 = sG[0];
    float s0 = 0.0f;
#pragma unroll
    for (int w = 0; w < 4; ++w) {
      int gw = sG[w];
      if (gw < 0) continue;
      if (gw == g0) s0 += sO[w][t];
      else atomicAdd(&base[gw * 64 + t], sO[w][t]);  // rare: graph boundary
    }
    if (g0 >= 0) atomicAdd(&base[g0 * 64 + t], s0);
  }
}

// reduce 256 BN replicas -> scale/shift
__global__ void bn_final_kernel(const float* __restrict__ bnsR, const float* __restrict__ gamma,
                                const float* __restrict__ beta, float* __restrict__ ss, int n) {
  __shared__ float red[128];
  int t = threadIdx.x;  // 128 threads
  float s = 0.0f;
  for (int r = 0; r < 256; ++r) s += bnsR[r * 128 + t];
  red[t] = s;
  __syncthreads();
  if (t < 64) {
    float inv_n = 1.0f / (float)n;
    float mu = red[t] * inv_n;
    float var = red[64 + t] * inv_n - mu * mu;
    var = fmaxf(var, 0.0f);
    float sc = gamma[t] * rsqrtf(var + 1e-5f);
    ss[t] = sc;
    ss[64 + t] = beta[t] - mu * sc;
  }
}

// reduce 16 pool replicas, divide by count
__global__ void pool_final_kernel(const float* __restrict__ poolR, const int* __restrict__ cnt,
                                  float* __restrict__ out) {
  int idx = blockIdx.x * 256 + threadIdx.x;  // 4096 total
  float s = 0.0f;
  for (int r = 0; r < 16; ++r) s += poolR[r * 4096 + idx];
  int g = idx >> 6;
  float c = (float)cnt[g];
  out[idx] = s / fmaxf(c, 1.0f);
}

extern "C" void kernel_launch(void* const* d_in, const int* in_sizes, int n_in,
                              void* d_out, int out_size, void* d_ws, size_t ws_size,
                              hipStream_t stream) {
  const float* x = (const float*)d_in[0];
  const int* ei = (const int*)d_in[1];
  const int* batch = (const int*)d_in[2];
  const float* W1 = (const float*)d_in[3];
  const float* b1 = (const float*)d_in[4];
  const float* gamma = (const float*)d_in[5];
  const float* beta = (const float*)d_in[6];
  const float* W2 = (const float*)d_in[7];
  const float* b2 = (const float*)d_in[8];

  const int n = in_sizes[0] / 64;
  const int E = in_sizes[1] / 2;
  const int* srcp = ei;
  const int* dstp = ei + E;

  int nblkP = (E + EPB - 1) / EPB;    // 196 partition blocks
  int nbuck = (n + 255) >> 8;         // 196 buckets (needs n <= 65536)
  int S = nbuck * nblkP;              // 38416 counters
  int nbt = (S + 255) / 256;          // 151 scan tiles (<= 256)
  int gridRows = (n + 3) / 4;

  float* ws = (float*)d_ws;
  size_t nf = (size_t)n * 64;
  float* bufA = ws;                   // h1, then h2'
  float* bufB = ws + nf;              // pre-BN h
  float* dinv = ws + 2 * nf;          // n floats
  float* ss = dinv + n;               // 128
  int* rowptr = (int*)(ss + 128);     // n+1
  int* col = rowptr + n + 1;          // E
  int* part = col + E;                // E (own region: bufA live during preproc)
  int* hist = part + E;               // S+1
  int* bsum = hist + S + 1;           // nbt (<=256)
  float* bnsR = (float*)(bsum + 256); // 256*128  (zero region starts here)
  float* poolR = bnsR + 256 * 128;    // 16*4096
  int* cnti = (int*)(poolR + 16 * 4096);  // 64   (zero region ends here)

  float* out = (float*)d_out;  // FLOAT32 output

  size_t zbytes = (size_t)((char*)(cnti + 64) - (char*)bnsR);
  hipMemsetAsync(bnsR, 0, zbytes, stream);

  int blk = 256;
  int fatGrid = nblkP + CNTB + gridRows;

  fat_phist_cnt_mm64_kernel<<<fatGrid, blk, 0, stream>>>(
      dstp, batch, hist, cnti, x, W1, bufA, E, n, nblkP, nbuck);
  scan1_kernel<<<nbt, blk, 0, stream>>>(hist, hist, bsum, S);
  scan_add2_kernel<<<nbt, blk, 0, stream>>>(hist, bsum, S, nbt);
  part_kernel<<<nblkP, blk, 0, stream>>>(srcp, dstp, hist, part, E, n, nblkP, nbuck);
  csr_kernel<<<nbuck, blk, 0, stream>>>(part, hist, rowptr, dinv, col, n, nblkP, nbuck);

  gather_bn_kernel<<<gridRows, blk, 0, stream>>>(rowptr, col, dinv, bufA, b1, bufB, bnsR, n);
  bn_final_kernel<<<1, 128, 0, stream>>>(bnsR, gamma, beta, ss, n);
  bn_elu_mm64_kernel<<<gridRows, blk, 0, stream>>>(bufB, W2, ss, bufA, n);
  gather_pool_kernel<<<gridRows, blk, 0, stream>>>(rowptr, col, dinv, bufA, b2, out, batch,
                                                   poolR, n);
  pool_final_kernel<<<16, blk, 0, stream>>>(poolR, cnti, out + nf);
}